// Round 6
// baseline (6876.907 us; speedup 1.0000x reference)
//
#include <hip/hip_runtime.h>
#include <cstdint>

// ---- problem constants ----
#define B_    2
#define L_    4
#define N_    2048
#define M_    1024
#define K_    32
#define DIV_  4
#define S_    8
#define F1_   128
#define PF_   64
#define CIN_  192
#define OUT_  256
#define EPS_  1e-5f

#define BL_   (B_*L_)          // 8
#define BLM_  (BL_*M_)         // 8192
#define NPTS_ (BLM_*K_)        // 262144
#define ROWS_ (BLM_*DIV_)      // 32768

// ---- workspace layout (float offsets) ----
#define OFF_FM   0              // 6291456   fm: [BLM][4][192]
#define OFF_IDX  6291456        // 262144    idx (int)
#define OFF_LOC  6553600        // 1048576   local4: [NPTS][4]
#define OFF_W1F  7602176        // 96
#define OFF_B1F  7602272        // 32
#define OFF_W2F  7602304        // 2048
#define OFF_B2F  7604352        // 64
#define OFF_WCT  7604416        // 196608    wcfT: [768][256]
#define OFF_BCF  7801024        // 256
#define OFF_P1   7801280        // 256       (32 blocks x 8)
#define OFF_P2   7801536        // 16384     (256 blocks x 64)
#define OFF_P3   7817920        // 49152     (128 blocks x 384)

// =====================================================================
// K1: per-(b,l) KNN.
// Selection key is LEXICOGRAPHIC:
//   primary   = expanded-f32 d2 = (qn + pn) - 2*cross   (no FMA,
//               left-assoc — matches the np gold's expanded arithmetic;
//               carries the cancellation noise the gold carries)
//   secondary = f64 direct d2 (essentially exact) — breaks EXACT
//               expanded-f32 ties in TRUE distance order (matching the
//               gold's observed tie resolution)
//   tertiary  = lower index first
// =====================================================================
__global__ __launch_bounds__(256) void k_knn(const float* __restrict__ points,
                                             const float* __restrict__ queries,
                                             int*   __restrict__ idxbuf,
                                             float* __restrict__ local4,
                                             float* __restrict__ p1)
{
#pragma clang fp contract(off)
    __shared__ float px[N_], py[N_], pz[N_], pnf[N_];
    __shared__ unsigned           kA[K_][256];
    __shared__ unsigned long long kB[K_][256];
    __shared__ float red[4][8];

    const int t  = threadIdx.x;
    const int bl = blockIdx.x >> 2;
    const int m  = ((blockIdx.x & 3) << 8) + t;

    const float* P = points  + (size_t)bl * (N_*3);
    const float* Q = queries + (size_t)bl * (M_*3);

    for (int j = t; j < N_*3; j += 256) {
        float v = P[j];
        int n = j / 3, i = j - 3*n;
        if (i == 0) px[n] = v; else if (i == 1) py[n] = v; else pz[n] = v;
    }
    __syncthreads();
    for (int n = t; n < N_; n += 256) {
        float x = px[n], y = py[n], z = pz[n];
        pnf[n] = (x*x + y*y) + z*z;          // left-assoc, no FMA
    }
    for (int j = 0; j < K_; ++j) { kA[j][t] = 0xFFFFFFFFu; kB[j][t] = ~0ULL; }
    __syncthreads();

    const float qx = Q[m*3], qy = Q[m*3+1], qz = Q[m*3+2];
    const float qn = (qx*qx + qy*qy) + qz*qz;
    const double qxd = (double)qx, qyd = (double)qy, qzd = (double)qz;

    unsigned kmaxA = 0xFFFFFFFFu;
    unsigned long long kmaxB = ~0ULL;
    for (int n = 0; n < N_; ++n) {
        const float pxn = px[n], pyn = py[n], pzn = pz[n];
        // primary: expanded f32, no FMA, left-assoc
        float cross = (qx*pxn + qy*pyn) + qz*pzn;
        float d2f = (qn + pnf[n]) - 2.0f*cross;
        unsigned uA = __float_as_uint(d2f);
        uA = (uA & 0x80000000u) ? ~uA : (uA | 0x80000000u);
        // secondary: f64 direct (exact ordering for all practical gaps)
        double dx = qxd - (double)pxn, dy = qyd - (double)pyn, dz = qzd - (double)pzn;
        double d2d = dx*dx + dy*dy + dz*dz;
        unsigned long long uB = (unsigned long long)__double_as_longlong(d2d);
        uB = (uB & 0x8000000000000000ULL) ? ~uB : (uB | 0x8000000000000000ULL);
        uB = (uB & ~2047ULL) | (unsigned long long)n;   // tertiary: index

        if (uA < kmaxA || (uA == kmaxA && uB < kmaxB)) {
            int j = K_-1;
            while (j > 0) {
                unsigned a1 = kA[j-1][t]; unsigned long long a2 = kB[j-1][t];
                if (a1 > uA || (a1 == uA && a2 > uB)) {
                    kA[j][t] = a1; kB[j][t] = a2; --j;
                } else break;
            }
            kA[j][t] = uA; kB[j][t] = uB;
            kmaxA = kA[K_-1][t]; kmaxB = kB[K_-1][t];
        }
    }

    float sx=0,sy=0,sz=0,s2x=0,s2y=0,s2z=0;
    const long long base = ((long long)bl * M_ + m) * K_;
    for (int j = 0; j < K_; ++j) {
        unsigned n = (unsigned)(kB[j][t] & 2047ULL);
        idxbuf[base + j] = (int)n;
        float lx = qx - px[n], ly = qy - py[n], lz = qz - pz[n];
        float* o = local4 + (base + j)*4;
        o[0]=lx; o[1]=ly; o[2]=lz; o[3]=0.f;
        sx+=lx; sy+=ly; sz+=lz; s2x+=lx*lx; s2y+=ly*ly; s2z+=lz*lz;
    }
    for (int off = 32; off; off >>= 1) {
        sx  += __shfl_down(sx,  off); sy  += __shfl_down(sy,  off); sz  += __shfl_down(sz,  off);
        s2x += __shfl_down(s2x, off); s2y += __shfl_down(s2y, off); s2z += __shfl_down(s2z, off);
    }
    const int wave = t >> 6;
    if ((t & 63) == 0) {
        red[wave][0]=sx; red[wave][1]=sy; red[wave][2]=sz;
        red[wave][3]=s2x; red[wave][4]=s2y; red[wave][5]=s2z;
    }
    __syncthreads();
    if (t == 0) {
        for (int i = 0; i < 6; ++i)
            p1[blockIdx.x*8 + i] = red[0][i]+red[1][i]+red[2][i]+red[3][i];
    }
}

// =====================================================================
// fold1: bn1 stats -> fold into w1/b1
// =====================================================================
__global__ void k_fold1(const float* __restrict__ p1,
                        const float* __restrict__ w1, const float* __restrict__ b1,
                        const float* __restrict__ g,  const float* __restrict__ bb,
                        float* __restrict__ w1f, float* __restrict__ b1f)
{
    __shared__ float s1[3], t1[3];
    int t = threadIdx.x;
    if (t < 3) {
        float S = 0, Q = 0;
        for (int b = 0; b < 32; ++b) { S += p1[b*8+t]; Q += p1[b*8+3+t]; }
        float mean = S / (float)NPTS_;
        float var  = Q / (float)NPTS_ - mean*mean;
        float r = 1.0f / sqrtf(var + EPS_);
        float sc = r * g[t];
        s1[t] = sc; t1[t] = bb[t] - mean*sc;
    }
    __syncthreads();
    if (t < 32) {
        float acc = b1[t];
        for (int i = 0; i < 3; ++i) {
            float w = w1[t*3+i];
            w1f[t*3+i] = w * s1[i];
            acc += w * t1[i];
        }
        b1f[t] = acc;
    }
}

// =====================================================================
// K2: bn2 stats (recompute h1 = relu(w1f.local + b1f))
// =====================================================================
__global__ __launch_bounds__(256) void k_stats2(const float* __restrict__ local4,
                                                const float* __restrict__ w1f,
                                                const float* __restrict__ b1f,
                                                float* __restrict__ p2)
{
    __shared__ float ws[96], bs[32];
    __shared__ float red[256][33];
    int t = threadIdx.x;
    for (int j = t; j < 96; j += 256) ws[j] = w1f[j];
    if (t < 32) bs[t] = b1f[t];
    __syncthreads();

    float s[32], q[32];
#pragma unroll
    for (int o = 0; o < 32; ++o) { s[o] = 0.f; q[o] = 0.f; }
    const int base = blockIdx.x * 1024;
    for (int i = 0; i < 4; ++i) {
        const float4 v = *(const float4*)(local4 + (size_t)(base + i*256 + t) * 4);
#pragma unroll
        for (int o = 0; o < 32; ++o) {
            float h = fmaxf(bs[o] + ws[o*3]*v.x + ws[o*3+1]*v.y + ws[o*3+2]*v.z, 0.f);
            s[o] += h; q[o] += h*h;
        }
    }
#pragma unroll
    for (int o = 0; o < 32; ++o) red[t][o] = s[o];
    __syncthreads();
    for (int h = 128; h > 0; h >>= 1) {
        if (t < h) { for (int o = 0; o < 32; ++o) red[t][o] += red[t+h][o]; }
        __syncthreads();
    }
    if (t < 32) p2[blockIdx.x*64 + t] = red[0][t];
    __syncthreads();
#pragma unroll
    for (int o = 0; o < 32; ++o) red[t][o] = q[o];
    __syncthreads();
    for (int h = 128; h > 0; h >>= 1) {
        if (t < h) { for (int o = 0; o < 32; ++o) red[t][o] += red[t+h][o]; }
        __syncthreads();
    }
    if (t < 32) p2[blockIdx.x*64 + 32 + t] = red[0][t];
}

// =====================================================================
// fold2: bn2 stats -> fold into w2/b2
// =====================================================================
__global__ void k_fold2(const float* __restrict__ p2,
                        const float* __restrict__ w2, const float* __restrict__ b2,
                        const float* __restrict__ g,  const float* __restrict__ bb,
                        float* __restrict__ w2f, float* __restrict__ b2f)
{
    __shared__ float s2[32], t2[32];
    int t = threadIdx.x;   // 64
    if (t < 32) {
        float S = 0, Q = 0;
        for (int b = 0; b < 256; ++b) { S += p2[b*64+t]; Q += p2[b*64+32+t]; }
        float mean = S / (float)NPTS_;
        float var  = Q / (float)NPTS_ - mean*mean;
        float r = 1.0f / sqrtf(var + EPS_);
        float sc = r * g[t];
        s2[t] = sc; t2[t] = bb[t] - mean*sc;
    }
    __syncthreads();
    float acc = b2[t];
    for (int i = 0; i < 32; ++i) {
        float w = w2[t*32+i];
        w2f[t*32+i] = w * s2[i];
        acc += w * t2[i];
    }
    b2f[t] = acc;
}

// =====================================================================
// K3: per-(b,l,m): h1 -> h2, gather feat_prev, shell maxpool -> fm row
// =====================================================================
__global__ __launch_bounds__(256) void k_shell(const float* __restrict__ feat_prev,
                                               const int*   __restrict__ idxbuf,
                                               const float* __restrict__ local4,
                                               const float* __restrict__ w1f,
                                               const float* __restrict__ b1f,
                                               const float* __restrict__ w2f,
                                               const float* __restrict__ b2f,
                                               float* __restrict__ fm)
{
    __shared__ float w1s[96], b1s[32], w2s[32][64], b2s[64];
    __shared__ int   idxs[K_];
    __shared__ float locs[K_][4];
    __shared__ float h1s[K_][33];
    __shared__ float h2s[K_][65];
    __shared__ float fmrow[DIV_][CIN_];

    const int t = threadIdx.x;
    const int blm = blockIdx.x;
    const long long base = (long long)blm * K_;

    for (int j = t; j < 96; j += 256) w1s[j] = w1f[j];
    if (t < 32) b1s[t] = b1f[t];
    if (t < 64) b2s[t] = b2f[t];
    for (int j = t; j < 2048; j += 256) { int i = j >> 6, o = j & 63; w2s[i][o] = w2f[o*32 + i]; }
    if (t < 32)  idxs[t] = idxbuf[base + t];
    if (t < 128) ((float*)locs)[t] = local4[base*4 + t];
    __syncthreads();

    for (int j = t; j < 1024; j += 256) {
        int k = j >> 5, o = j & 31;
        float v = b1s[o] + w1s[o*3]*locs[k][0] + w1s[o*3+1]*locs[k][1] + w1s[o*3+2]*locs[k][2];
        h1s[k][o] = fmaxf(v, 0.f);
    }
    __syncthreads();
    for (int j = t; j < 2048; j += 256) {
        int k = j >> 6, o = j & 63;
        float acc = b2s[o];
#pragma unroll
        for (int i = 0; i < 32; ++i) acc += h1s[k][i] * w2s[i][o];
        h2s[k][o] = fmaxf(acc, 0.f);
    }
    __syncthreads();
    {
        int d = t >> 6, o = t & 63;
        float mx = h2s[d*8][o];
#pragma unroll
        for (int j = 1; j < 8; ++j) mx = fmaxf(mx, h2s[d*8+j][o]);
        fmrow[d][o] = mx;
    }
    {
        const float* fp0 = feat_prev + (size_t)(blm / M_) * N_ * F1_;
#pragma unroll
        for (int ph = 0; ph < 2; ++ph) {
            int d = ph*2 + (t >> 7), c = t & 127;
            float mx = -3.4e38f;
#pragma unroll
            for (int j = 0; j < 8; ++j) {
                int n = idxs[d*8+j];
                mx = fmaxf(mx, fp0[(size_t)n*F1_ + c]);
            }
            fmrow[d][64 + c] = mx;
        }
    }
    __syncthreads();
    for (int j = t; j < DIV_*CIN_; j += 256)
        fm[(long long)blm * (DIV_*CIN_) + j] = (&fmrow[0][0])[j];
}

// =====================================================================
// K3s: bnc stats over fm (32768 rows x 192 ch)
// =====================================================================
__global__ void k_stats3(const float* __restrict__ fm, float* __restrict__ p3)
{
    const int t = threadIdx.x;     // 192
    const int blk = blockIdx.x;    // 128
    float s = 0.f, q = 0.f;
    const size_t base = (size_t)blk * 256 * CIN_;
    for (int r = 0; r < 256; ++r) {
        float v = fm[base + (size_t)r*CIN_ + t];
        s += v; q += v*v;
    }
    p3[blk*384 + t] = s;
    p3[blk*384 + 192 + t] = q;
}

// =====================================================================
// fold3: bnc stats -> scaled transposed conv weights + effective bias
// =====================================================================
__global__ __launch_bounds__(256) void k_fold3(const float* __restrict__ p3,
                                               const float* __restrict__ conv_w,
                                               const float* __restrict__ conv_b,
                                               const float* __restrict__ g,
                                               const float* __restrict__ bb,
                                               float* __restrict__ wcfT,
                                               float* __restrict__ bcf)
{
    __shared__ float sc[CIN_], tc[CIN_];
    const int t = threadIdx.x;
    if (t < CIN_) {
        float S = 0, Q = 0;
        for (int b = 0; b < 128; ++b) { S += p3[b*384+t]; Q += p3[b*384+192+t]; }
        float mean = S / (float)ROWS_;
        float var  = Q / (float)ROWS_ - mean*mean;
        float r = 1.0f / sqrtf(var + EPS_);
        float s = r * g[t];
        sc[t] = s; tc[t] = bb[t] - mean*s;
    }
    __syncthreads();
    // fill this block's chunk of wcfT  (64 blocks x 3072)
    const int lo = blockIdx.x * 3072;
    for (int j = lo + t; j < lo + 3072; j += 256) {
        int o = j & 255, row = j >> 8;
        int c = row % CIN_, d = row / CIN_;
        wcfT[j] = conv_w[o*768 + c*4 + d] * sc[c];
    }
    if (blockIdx.x == 0) {
        float acc = conv_b[t];
        for (int c = 0; c < CIN_; ++c) {
            float tcv = tc[c];
#pragma unroll
            for (int d = 0; d < 4; ++d) acc += tcv * conv_w[t*768 + c*4 + d];
        }
        bcf[t] = acc;
    }
}

// =====================================================================
// K4: GEMM  C(8192x256) = fm(8192x768) * wcfT(768x256) + bcf
// =====================================================================
__global__ __launch_bounds__(256) void k_gemm(const float* __restrict__ A,
                                              const float* __restrict__ W,
                                              const float* __restrict__ bias,
                                              float* __restrict__ C)
{
    __shared__ __align__(16) float At[32][68];
    __shared__ __align__(16) float Wt[32][64];
    const int tx = threadIdx.x, ty = threadIdx.y;
    const int t = ty*16 + tx;
    const int row0 = blockIdx.x * 64, col0 = blockIdx.y * 64;

    float acc[4][4];
#pragma unroll
    for (int i = 0; i < 4; ++i)
#pragma unroll
        for (int j = 0; j < 4; ++j) acc[i][j] = 0.f;

    for (int kt = 0; kt < 24; ++kt) {
#pragma unroll
        for (int i = 0; i < 8; ++i) {
            int j = i*256 + t; int r = j >> 5, k = j & 31;
            At[k][r] = A[(size_t)(row0 + r)*768 + kt*32 + k];
        }
#pragma unroll
        for (int i = 0; i < 8; ++i) {
            int j = i*256 + t; int k = j >> 6, c = j & 63;
            Wt[k][c] = W[(size_t)(kt*32 + k)*256 + col0 + c];
        }
        __syncthreads();
#pragma unroll
        for (int k = 0; k < 32; ++k) {
            float4 a = *(const float4*)&At[k][ty*4];
            float4 w = *(const float4*)&Wt[k][tx*4];
            acc[0][0] += a.x*w.x; acc[0][1] += a.x*w.y; acc[0][2] += a.x*w.z; acc[0][3] += a.x*w.w;
            acc[1][0] += a.y*w.x; acc[1][1] += a.y*w.y; acc[1][2] += a.y*w.z; acc[1][3] += a.y*w.w;
            acc[2][0] += a.z*w.x; acc[2][1] += a.z*w.y; acc[2][2] += a.z*w.z; acc[2][3] += a.z*w.w;
            acc[3][0] += a.w*w.x; acc[3][1] += a.w*w.y; acc[3][2] += a.w*w.z; acc[3][3] += a.w*w.w;
        }
        __syncthreads();
    }

    float b4[4];
#pragma unroll
    for (int j = 0; j < 4; ++j) b4[j] = bias[col0 + tx*4 + j];
#pragma unroll
    for (int i = 0; i < 4; ++i) {
        int r = row0 + ty*4 + i;
        float4 o4;
        o4.x = acc[i][0] + b4[0];
        o4.y = acc[i][1] + b4[1];
        o4.z = acc[i][2] + b4[2];
        o4.w = acc[i][3] + b4[3];
        *(float4*)&C[(size_t)r*256 + col0 + tx*4] = o4;
    }
}

// =====================================================================
extern "C" void kernel_launch(void* const* d_in, const int* in_sizes, int n_in,
                              void* d_out, int out_size, void* d_ws, size_t ws_size,
                              hipStream_t stream)
{
    const float* points    = (const float*)d_in[0];
    const float* queries   = (const float*)d_in[1];
    const float* feat_prev = (const float*)d_in[2];
    const float* bn1g = (const float*)d_in[3];
    const float* bn1b = (const float*)d_in[4];
    const float* w1   = (const float*)d_in[5];
    const float* b1   = (const float*)d_in[6];
    const float* bn2g = (const float*)d_in[7];
    const float* bn2b = (const float*)d_in[8];
    const float* w2   = (const float*)d_in[9];
    const float* b2   = (const float*)d_in[10];
    const float* bncg = (const float*)d_in[11];
    const float* bncb = (const float*)d_in[12];
    const float* convw= (const float*)d_in[13];
    const float* convb= (const float*)d_in[14];

    float* ws   = (float*)d_ws;
    float* fm   = ws + OFF_FM;
    int*   idxb = (int*)(ws + OFF_IDX);
    float* loc4 = ws + OFF_LOC;
    float* w1f  = ws + OFF_W1F;
    float* b1f  = ws + OFF_B1F;
    float* w2f  = ws + OFF_W2F;
    float* b2f  = ws + OFF_B2F;
    float* wct  = ws + OFF_WCT;
    float* bcf  = ws + OFF_BCF;
    float* p1   = ws + OFF_P1;
    float* p2   = ws + OFF_P2;
    float* p3   = ws + OFF_P3;

    k_knn   <<<32, 256, 0, stream>>>(points, queries, idxb, loc4, p1);
    k_fold1 <<<1, 64, 0, stream>>>(p1, w1, b1, bn1g, bn1b, w1f, b1f);
    k_stats2<<<256, 256, 0, stream>>>(loc4, w1f, b1f, p2);
    k_fold2 <<<1, 64, 0, stream>>>(p2, w2, b2, bn2g, bn2b, w2f, b2f);
    k_shell <<<BLM_, 256, 0, stream>>>(feat_prev, idxb, loc4, w1f, b1f, w2f, b2f, fm);
    k_stats3<<<128, 192, 0, stream>>>(fm, p3);
    k_fold3 <<<64, 256, 0, stream>>>(p3, convw, convb, bncg, bncb, wct, bcf);
    k_gemm  <<<dim3(128, 4), dim3(16, 16), 0, stream>>>(fm, wct, bcf, (float*)d_out);
}

// Round 8
// 403.487 us; speedup vs baseline: 17.0437x; 17.0437x over previous
//
#include <hip/hip_runtime.h>
#include <cstdint>

// ---- problem constants ----
#define B_    2
#define L_    4
#define N_    2048
#define M_    1024
#define K_    32
#define DIV_  4
#define S_    8
#define F1_   128
#define PF_   64
#define CIN_  192
#define OUT_  256
#define EPS_  1e-5f

#define BL_   (B_*L_)          // 8
#define BLM_  (BL_*M_)         // 8192
#define NPTS_ (BLM_*K_)        // 262144
#define ROWS_ (BLM_*DIV_)      // 32768

// ---- workspace layout (float offsets) ----
#define OFF_FM   0              // 6291456   fm: [BLM][4][192]  (p1 aliases its head pre-k_shell)
#define OFF_IDX  6291456        // 262144    idx (int)
#define OFF_LOC  6553600        // 1048576   local4: [NPTS][4]
#define OFF_W1F  7602176        // 96
#define OFF_B1F  7602272        // 32
#define OFF_W2F  7602304        // 2048
#define OFF_B2F  7604352        // 64
#define OFF_WCT  7604416        // 196608    wcfT: [768][256]
#define OFF_BCF  7801024        // 256
#define OFF_P2   7801536        // 16384     (256 blocks x 64)
#define OFF_P3   7817920        // 49152     (128 blocks x 384)

__device__ __forceinline__ unsigned long long shfl_xor_u64(unsigned long long v, int m)
{
    unsigned lo = (unsigned)v, hi = (unsigned)(v >> 32);
    lo = __shfl_xor(lo, m); hi = __shfl_xor(hi, m);
    return ((unsigned long long)hi << 32) | lo;
}
__device__ __forceinline__ unsigned long long shfl_u64(unsigned long long v, int src)
{
    unsigned lo = (unsigned)v, hi = (unsigned)(v >> 32);
    lo = __shfl(lo, src); hi = __shfl(hi, src);
    return ((unsigned long long)hi << 32) | lo;
}

// =====================================================================
// K1: wave-per-query KNN, lane-distributed bitonic top-32 (scalar state,
// no register arrays -> small code, fast compile).
// Key semantics IDENTICAL to the passing round-6 kernel:
//   primary   uA = ordered-bits of expanded-f32 d2 = (qn+pn) - 2*cross
//             (no FMA, left-assoc, contract(off))
//   secondary uB = ordered-bits of f64 direct d2, low 11 bits = index
// Lanes 0..31 hold the running top-32 ascending; lanes 32..63 hold +inf.
// Per 64-candidate round: ballot skip-test, 64-lane bitonic sort of the
// candidates, lower-half merge M_i = min(A_i, S_{31-i}), 5-step resort.
// All keys distinct -> result equals round-6's insertion-sort output.
// =====================================================================
__global__ __launch_bounds__(256) void k_knn(const float* __restrict__ points,
                                             const float* __restrict__ queries,
                                             int*   __restrict__ idxbuf,
                                             float* __restrict__ local4,
                                             float* __restrict__ p1)
{
#pragma clang fp contract(off)
    __shared__ float4 pt[N_];          // x,y,z,pn  (32 KB)
    __shared__ float  wred[4][8];

    const int t    = threadIdx.x;
    const int lane = t & 63;
    const int wv   = t >> 6;
    const int bl   = blockIdx.x >> 8;            // 256 WGs per bl
    const int m    = ((blockIdx.x & 255) << 2) + wv;

    const float* P = points  + (size_t)bl * (N_*3);
    const float* Q = queries + (size_t)bl * (M_*3);

    for (int n = t; n < N_; n += 256) {
        float x = P[n*3], y = P[n*3+1], z = P[n*3+2];
        float pn = (x*x + y*y) + z*z;            // left-assoc, no FMA
        pt[n] = make_float4(x, y, z, pn);
    }
    __syncthreads();

    const float qx = Q[m*3], qy = Q[m*3+1], qz = Q[m*3+2];
    const float qn = (qx*qx + qy*qy) + qz*qz;
    const double qxd = (double)qx, qyd = (double)qy, qzd = (double)qz;

    // distributed top-32 state: lane i of 0..31 = i-th smallest; 32..63 = +inf
    unsigned           Aa = 0xFFFFFFFFu;
    unsigned long long Ab = ~0ULL;

    for (int r = 0; r < 32; ++r) {
        const int n = r*64 + lane;
        const float4 p4 = pt[n];
        float cross = (qx*p4.x + qy*p4.y) + qz*p4.z;   // no FMA
        float d2f = (qn + p4.w) - 2.0f*cross;
        unsigned uA = __float_as_uint(d2f);
        uA = (uA & 0x80000000u) ? ~uA : (uA | 0x80000000u);
        double dx = qxd - (double)p4.x, dy = qyd - (double)p4.y, dz = qzd - (double)p4.z;
        double d2d = dx*dx + dy*dy + dz*dz;
        unsigned long long uB = (unsigned long long)__double_as_longlong(d2d);
        uB = (uB & 0x8000000000000000ULL) ? ~uB : (uB | 0x8000000000000000ULL);
        uB = (uB & ~2047ULL) | (unsigned long long)n;

        // skip round if no candidate beats the current 32nd-smallest
        unsigned           thrA = __shfl(Aa, 31);
        unsigned long long thrB = shfl_u64(Ab, 31);
        bool lt = (uA < thrA) || (uA == thrA && uB < thrB);
        if (__ballot(lt) == 0ULL) continue;

        // 64-lane bitonic sort of candidates (ascending by lane)
        unsigned sa = uA; unsigned long long sb = uB;
        for (int k = 2; k <= 64; k <<= 1) {
            for (int j = k >> 1; j >= 1; j >>= 1) {
                unsigned           pa = __shfl_xor(sa, j);
                unsigned long long pb = shfl_xor_u64(sb, j);
                bool pl = (pa < sa) || (pa == sa && pb < sb);
                bool wantMin = (((lane & k) == 0) == ((lane & j) == 0));
                if (pl == wantMin) { sa = pa; sb = pb; }
            }
        }

        // merge: M_i = min(A_i, S_{31-i}) on lanes 0..31
        int src = (31 - lane) & 63;
        unsigned           ba  = __shfl(sa, src);
        unsigned long long bb2 = shfl_u64(sb, src);
        if (lane < 32) {
            bool bless = (ba < Aa) || (ba == Aa && bb2 < Ab);
            if (bless) { Aa = ba; Ab = bb2; }
        }
        // resort (bitonic -> ascending) within lanes 0..31
        for (int j = 16; j >= 1; j >>= 1) {
            unsigned           pa = __shfl_xor(Aa, j);
            unsigned long long pb = shfl_xor_u64(Ab, j);
            bool pl = (pa < Aa) || (pa == Aa && pb < Ab);
            bool wantMin = ((lane & j) == 0);
            if (pl == wantMin) { Aa = pa; Ab = pb; }
        }
    }

    const long long base = ((long long)bl * M_ + m) * K_;
    float lx = 0.f, ly = 0.f, lz = 0.f;
    if (lane < 32) {
        const int n = (int)(Ab & 2047ULL);
        idxbuf[base + lane] = n;
        const float4 p4 = pt[n];
        lx = qx - p4.x; ly = qy - p4.y; lz = qz - p4.z;
        *(float4*)(local4 + (base + lane)*4) = make_float4(lx, ly, lz, 0.f);
    }
    float s0 = lx, s1 = ly, s2 = lz, s3 = lx*lx, s4 = ly*ly, s5 = lz*lz;
#pragma unroll
    for (int off = 32; off; off >>= 1) {
        s0 += __shfl_xor(s0, off); s1 += __shfl_xor(s1, off); s2 += __shfl_xor(s2, off);
        s3 += __shfl_xor(s3, off); s4 += __shfl_xor(s4, off); s5 += __shfl_xor(s5, off);
    }
    if (lane == 0) {
        wred[wv][0]=s0; wred[wv][1]=s1; wred[wv][2]=s2;
        wred[wv][3]=s3; wred[wv][4]=s4; wred[wv][5]=s5;
    }
    __syncthreads();
    if (t < 6)
        p1[(long long)blockIdx.x*8 + t] = wred[0][t]+wred[1][t]+wred[2][t]+wred[3][t];
}

// =====================================================================
// fold1: reduce 2048 WG partials, fold bn1 into w1/b1
// =====================================================================
__global__ __launch_bounds__(256) void k_fold1(const float* __restrict__ p1,
                        const float* __restrict__ w1, const float* __restrict__ b1,
                        const float* __restrict__ g,  const float* __restrict__ bb,
                        float* __restrict__ w1f, float* __restrict__ b1f)
{
    __shared__ float red[6][33];
    __shared__ float s1[3], t1[3];
    const int t = threadIdx.x;
    const int c = t >> 5, i = t & 31;
    if (c < 6) {
        float s = 0.f;
        for (int w = i; w < 2048; w += 32) s += p1[w*8 + c];
        red[c][i] = s;
    }
    __syncthreads();
    if (t < 3) {
        float S = 0.f, Q = 0.f;
        for (int k = 0; k < 32; ++k) { S += red[t][k]; Q += red[t+3][k]; }
        float mean = S / (float)NPTS_;
        float var  = Q / (float)NPTS_ - mean*mean;
        float r = 1.0f / sqrtf(var + EPS_);
        float sc = r * g[t];
        s1[t] = sc; t1[t] = bb[t] - mean*sc;
    }
    __syncthreads();
    if (t < 32) {
        float acc = b1[t];
        for (int i2 = 0; i2 < 3; ++i2) {
            float w = w1[t*3+i2];
            w1f[t*3+i2] = w * s1[i2];
            acc += w * t1[i2];
        }
        b1f[t] = acc;
    }
}

// =====================================================================
// K2: bn2 stats (recompute h1 = relu(w1f.local + b1f))
// =====================================================================
__global__ __launch_bounds__(256) void k_stats2(const float* __restrict__ local4,
                                                const float* __restrict__ w1f,
                                                const float* __restrict__ b1f,
                                                float* __restrict__ p2)
{
    __shared__ float ws[96], bs[32];
    __shared__ float red[256][33];
    int t = threadIdx.x;
    for (int j = t; j < 96; j += 256) ws[j] = w1f[j];
    if (t < 32) bs[t] = b1f[t];
    __syncthreads();

    float s[32], q[32];
#pragma unroll
    for (int o = 0; o < 32; ++o) { s[o] = 0.f; q[o] = 0.f; }
    const int base = blockIdx.x * 1024;
    for (int i = 0; i < 4; ++i) {
        const float4 v = *(const float4*)(local4 + (size_t)(base + i*256 + t) * 4);
#pragma unroll
        for (int o = 0; o < 32; ++o) {
            float h = fmaxf(bs[o] + ws[o*3]*v.x + ws[o*3+1]*v.y + ws[o*3+2]*v.z, 0.f);
            s[o] += h; q[o] += h*h;
        }
    }
#pragma unroll
    for (int o = 0; o < 32; ++o) red[t][o] = s[o];
    __syncthreads();
    for (int h = 128; h > 0; h >>= 1) {
        if (t < h) { for (int o = 0; o < 32; ++o) red[t][o] += red[t+h][o]; }
        __syncthreads();
    }
    if (t < 32) p2[blockIdx.x*64 + t] = red[0][t];
    __syncthreads();
#pragma unroll
    for (int o = 0; o < 32; ++o) red[t][o] = q[o];
    __syncthreads();
    for (int h = 128; h > 0; h >>= 1) {
        if (t < h) { for (int o = 0; o < 32; ++o) red[t][o] += red[t+h][o]; }
        __syncthreads();
    }
    if (t < 32) p2[blockIdx.x*64 + 32 + t] = red[0][t];
}

// =====================================================================
// fold2: bn2 stats -> fold into w2/b2
// =====================================================================
__global__ void k_fold2(const float* __restrict__ p2,
                        const float* __restrict__ w2, const float* __restrict__ b2,
                        const float* __restrict__ g,  const float* __restrict__ bb,
                        float* __restrict__ w2f, float* __restrict__ b2f)
{
    __shared__ float s2[32], t2[32];
    int t = threadIdx.x;   // 64
    if (t < 32) {
        float S = 0, Q = 0;
        for (int b = 0; b < 256; ++b) { S += p2[b*64+t]; Q += p2[b*64+32+t]; }
        float mean = S / (float)NPTS_;
        float var  = Q / (float)NPTS_ - mean*mean;
        float r = 1.0f / sqrtf(var + EPS_);
        float sc = r * g[t];
        s2[t] = sc; t2[t] = bb[t] - mean*sc;
    }
    __syncthreads();
    float acc = b2[t];
    for (int i = 0; i < 32; ++i) {
        float w = w2[t*32+i];
        w2f[t*32+i] = w * s2[i];
        acc += w * t2[i];
    }
    b2f[t] = acc;
}

// =====================================================================
// K3: per-(b,l,m): h1 -> h2, gather feat_prev, shell maxpool -> fm row
// =====================================================================
__global__ __launch_bounds__(256) void k_shell(const float* __restrict__ feat_prev,
                                               const int*   __restrict__ idxbuf,
                                               const float* __restrict__ local4,
                                               const float* __restrict__ w1f,
                                               const float* __restrict__ b1f,
                                               const float* __restrict__ w2f,
                                               const float* __restrict__ b2f,
                                               float* __restrict__ fm)
{
    __shared__ float w1s[96], b1s[32], w2s[32][64], b2s[64];
    __shared__ int   idxs[K_];
    __shared__ float locs[K_][4];
    __shared__ float h1s[K_][33];
    __shared__ float h2s[K_][65];
    __shared__ float fmrow[DIV_][CIN_];

    const int t = threadIdx.x;
    const int blm = blockIdx.x;
    const long long base = (long long)blm * K_;

    for (int j = t; j < 96; j += 256) w1s[j] = w1f[j];
    if (t < 32) b1s[t] = b1f[t];
    if (t < 64) b2s[t] = b2f[t];
    for (int j = t; j < 2048; j += 256) { int i = j >> 6, o = j & 63; w2s[i][o] = w2f[o*32 + i]; }
    if (t < 32)  idxs[t] = idxbuf[base + t];
    if (t < 128) ((float*)locs)[t] = local4[base*4 + t];
    __syncthreads();

    for (int j = t; j < 1024; j += 256) {
        int k = j >> 5, o = j & 31;
        float v = b1s[o] + w1s[o*3]*locs[k][0] + w1s[o*3+1]*locs[k][1] + w1s[o*3+2]*locs[k][2];
        h1s[k][o] = fmaxf(v, 0.f);
    }
    __syncthreads();
    for (int j = t; j < 2048; j += 256) {
        int k = j >> 6, o = j & 63;
        float acc = b2s[o];
#pragma unroll
        for (int i = 0; i < 32; ++i) acc += h1s[k][i] * w2s[i][o];
        h2s[k][o] = fmaxf(acc, 0.f);
    }
    __syncthreads();
    {
        int d = t >> 6, o = t & 63;
        float mx = h2s[d*8][o];
#pragma unroll
        for (int j = 1; j < 8; ++j) mx = fmaxf(mx, h2s[d*8+j][o]);
        fmrow[d][o] = mx;
    }
    {
        const float* fp0 = feat_prev + (size_t)(blm / M_) * N_ * F1_;
#pragma unroll
        for (int ph = 0; ph < 2; ++ph) {
            int d = ph*2 + (t >> 7), c = t & 127;
            float mx = -3.4e38f;
#pragma unroll
            for (int j = 0; j < 8; ++j) {
                int n = idxs[d*8+j];
                mx = fmaxf(mx, fp0[(size_t)n*F1_ + c]);
            }
            fmrow[d][64 + c] = mx;
        }
    }
    __syncthreads();
    for (int j = t; j < DIV_*CIN_; j += 256)
        fm[(long long)blm * (DIV_*CIN_) + j] = (&fmrow[0][0])[j];
}

// =====================================================================
// K3s: bnc stats over fm (32768 rows x 192 ch)
// =====================================================================
__global__ void k_stats3(const float* __restrict__ fm, float* __restrict__ p3)
{
    const int t = threadIdx.x;     // 192
    const int blk = blockIdx.x;    // 128
    float s = 0.f, q = 0.f;
    const size_t base = (size_t)blk * 256 * CIN_;
    for (int r = 0; r < 256; ++r) {
        float v = fm[base + (size_t)r*CIN_ + t];
        s += v; q += v*v;
    }
    p3[blk*384 + t] = s;
    p3[blk*384 + 192 + t] = q;
}

// =====================================================================
// fold3: bnc stats -> scaled transposed conv weights + effective bias
// =====================================================================
__global__ __launch_bounds__(256) void k_fold3(const float* __restrict__ p3,
                                               const float* __restrict__ conv_w,
                                               const float* __restrict__ conv_b,
                                               const float* __restrict__ g,
                                               const float* __restrict__ bb,
                                               float* __restrict__ wcfT,
                                               float* __restrict__ bcf)
{
    __shared__ float sc[CIN_], tc[CIN_];
    const int t = threadIdx.x;
    if (t < CIN_) {
        float S = 0, Q = 0;
        for (int b = 0; b < 128; ++b) { S += p3[b*384+t]; Q += p3[b*384+192+t]; }
        float mean = S / (float)ROWS_;
        float var  = Q / (float)ROWS_ - mean*mean;
        float r = 1.0f / sqrtf(var + EPS_);
        float s = r * g[t];
        sc[t] = s; tc[t] = bb[t] - mean*s;
    }
    __syncthreads();
    const int lo = blockIdx.x * 3072;
    for (int j = lo + t; j < lo + 3072; j += 256) {
        int o = j & 255, row = j >> 8;
        int c = row % CIN_, d = row / CIN_;
        wcfT[j] = conv_w[o*768 + c*4 + d] * sc[c];
    }
    if (blockIdx.x == 0) {
        float acc = conv_b[t];
        for (int c = 0; c < CIN_; ++c) {
            float tcv = tc[c];
#pragma unroll
            for (int d = 0; d < 4; ++d) acc += tcv * conv_w[t*768 + c*4 + d];
        }
        bcf[t] = acc;
    }
}

// =====================================================================
// K4: GEMM  C(8192x256) = fm(8192x768) * wcfT(768x256) + bcf
// =====================================================================
__global__ __launch_bounds__(256) void k_gemm(const float* __restrict__ A,
                                              const float* __restrict__ W,
                                              const float* __restrict__ bias,
                                              float* __restrict__ C)
{
    __shared__ __align__(16) float At[32][68];
    __shared__ __align__(16) float Wt[32][64];
    const int tx = threadIdx.x, ty = threadIdx.y;
    const int t = ty*16 + tx;
    const int row0 = blockIdx.x * 64, col0 = blockIdx.y * 64;

    float acc[4][4];
#pragma unroll
    for (int i = 0; i < 4; ++i)
#pragma unroll
        for (int j = 0; j < 4; ++j) acc[i][j] = 0.f;

    for (int kt = 0; kt < 24; ++kt) {
#pragma unroll
        for (int i = 0; i < 8; ++i) {
            int j = i*256 + t; int r = j >> 5, k = j & 31;
            At[k][r] = A[(size_t)(row0 + r)*768 + kt*32 + k];
        }
#pragma unroll
        for (int i = 0; i < 8; ++i) {
            int j = i*256 + t; int k = j >> 6, c = j & 63;
            Wt[k][c] = W[(size_t)(kt*32 + k)*256 + col0 + c];
        }
        __syncthreads();
#pragma unroll
        for (int k = 0; k < 32; ++k) {
            float4 a = *(const float4*)&At[k][ty*4];
            float4 w = *(const float4*)&Wt[k][tx*4];
            acc[0][0] += a.x*w.x; acc[0][1] += a.x*w.y; acc[0][2] += a.x*w.z; acc[0][3] += a.x*w.w;
            acc[1][0] += a.y*w.x; acc[1][1] += a.y*w.y; acc[1][2] += a.y*w.z; acc[1][3] += a.y*w.w;
            acc[2][0] += a.z*w.x; acc[2][1] += a.z*w.y; acc[2][2] += a.z*w.z; acc[2][3] += a.z*w.w;
            acc[3][0] += a.w*w.x; acc[3][1] += a.w*w.y; acc[3][2] += a.w*w.z; acc[3][3] += a.w*w.w;
        }
        __syncthreads();
    }

    float b4[4];
#pragma unroll
    for (int j = 0; j < 4; ++j) b4[j] = bias[col0 + tx*4 + j];
#pragma unroll
    for (int i = 0; i < 4; ++i) {
        int r = row0 + ty*4 + i;
        float4 o4;
        o4.x = acc[i][0] + b4[0];
        o4.y = acc[i][1] + b4[1];
        o4.z = acc[i][2] + b4[2];
        o4.w = acc[i][3] + b4[3];
        *(float4*)&C[(size_t)r*256 + col0 + tx*4] = o4;
    }
}

// =====================================================================
extern "C" void kernel_launch(void* const* d_in, const int* in_sizes, int n_in,
                              void* d_out, int out_size, void* d_ws, size_t ws_size,
                              hipStream_t stream)
{
    const float* points    = (const float*)d_in[0];
    const float* queries   = (const float*)d_in[1];
    const float* feat_prev = (const float*)d_in[2];
    const float* bn1g = (const float*)d_in[3];
    const float* bn1b = (const float*)d_in[4];
    const float* w1   = (const float*)d_in[5];
    const float* b1   = (const float*)d_in[6];
    const float* bn2g = (const float*)d_in[7];
    const float* bn2b = (const float*)d_in[8];
    const float* w2   = (const float*)d_in[9];
    const float* b2   = (const float*)d_in[10];
    const float* bncg = (const float*)d_in[11];
    const float* bncb = (const float*)d_in[12];
    const float* convw= (const float*)d_in[13];
    const float* convb= (const float*)d_in[14];

    float* ws   = (float*)d_ws;
    float* fm   = ws + OFF_FM;
    int*   idxb = (int*)(ws + OFF_IDX);
    float* loc4 = ws + OFF_LOC;
    float* w1f  = ws + OFF_W1F;
    float* b1f  = ws + OFF_B1F;
    float* w2f  = ws + OFF_W2F;
    float* b2f  = ws + OFF_B2F;
    float* wct  = ws + OFF_WCT;
    float* bcf  = ws + OFF_BCF;
    float* p1   = ws + OFF_FM;     // aliases fm head; consumed by fold1 before k_shell writes fm
    float* p2   = ws + OFF_P2;
    float* p3   = ws + OFF_P3;

    k_knn   <<<2048, 256, 0, stream>>>(points, queries, idxb, loc4, p1);
    k_fold1 <<<1, 256, 0, stream>>>(p1, w1, b1, bn1g, bn1b, w1f, b1f);
    k_stats2<<<256, 256, 0, stream>>>(loc4, w1f, b1f, p2);
    k_fold2 <<<1, 64, 0, stream>>>(p2, w2, b2, bn2g, bn2b, w2f, b2f);
    k_shell <<<BLM_, 256, 0, stream>>>(feat_prev, idxb, loc4, w1f, b1f, w2f, b2f, fm);
    k_stats3<<<128, 192, 0, stream>>>(fm, p3);
    k_fold3 <<<64, 256, 0, stream>>>(p3, convw, convb, bncg, bncb, wct, bcf);
    k_gemm  <<<dim3(128, 4), dim3(16, 16), 0, stream>>>(fm, wct, bcf, (float*)d_out);
}

// Round 9
// 243.747 us; speedup vs baseline: 28.2133x; 1.6554x over previous
//
#include <hip/hip_runtime.h>
#include <cstdint>

// ---- problem constants ----
#define B_    2
#define L_    4
#define N_    2048
#define M_    1024
#define K_    32
#define DIV_  4
#define S_    8
#define F1_   128
#define PF_   64
#define CIN_  192
#define OUT_  256
#define EPS_  1e-5f

#define BL_   (B_*L_)          // 8
#define BLM_  (BL_*M_)         // 8192
#define NPTS_ (BLM_*K_)        // 262144
#define ROWS_ (BLM_*DIV_)      // 32768

// ---- workspace layout (float offsets) ----
#define OFF_FM   0              // 6291456   fm: [BLM][4][192]  (p1 aliases its head pre-k_shell)
#define OFF_IDX  6291456        // 262144    idx (int)
#define OFF_LOC  6553600        // 1048576   local4: [NPTS][4]
#define OFF_W1F  7602176        // 96
#define OFF_B1F  7602272        // 32
#define OFF_W2F  7602304        // 2048
#define OFF_B2F  7604352        // 64
#define OFF_WCT  7604416        // 196608    wcfT: [768][256]
#define OFF_BCF  7801024        // 256
#define OFF_P2   7801536        // 16384     (256 blocks x 64)
#define OFF_P3   7817920        // 49152     (128 blocks x 384)

__device__ __forceinline__ unsigned long long shfl_xor_u64(unsigned long long v, int m)
{
    unsigned lo = (unsigned)v, hi = (unsigned)(v >> 32);
    lo = __shfl_xor(lo, m); hi = __shfl_xor(hi, m);
    return ((unsigned long long)hi << 32) | lo;
}
__device__ __forceinline__ unsigned long long shfl_u64(unsigned long long v, int src)
{
    unsigned lo = (unsigned)v, hi = (unsigned)(v >> 32);
    lo = __shfl(lo, src); hi = __shfl(hi, src);
    return ((unsigned long long)hi << 32) | lo;
}

// =====================================================================
// K1: wave-per-query KNN, lane-distributed top-32 with filter + batched
// bitonic rebuild.
// Key semantics IDENTICAL to the passing round-6/8 kernels:
//   primary   uA = ordered-bits of expanded-f32 d2 = (qn+pn) - 2*cross
//             (no FMA, left-assoc, contract(off))
//   secondary uB = ordered-bits of f64 direct d2, low 11 bits = index
// Per 64-candidate round: compare against running 32nd-smallest
// (register threshold), ballot+prefix-popcount compaction of survivors
// into a 64-slot LDS buffer. On (would-)overflow and at the end: 64-lane
// bitonic sort of the buffer, lower-half merge M_i = min(A_i, S_{31-i}),
// 5-step resort, threshold update. All keys distinct -> identical total
// order -> idx/local outputs bit-identical to round 8.
// =====================================================================
__global__ __launch_bounds__(256) void k_knn(const float* __restrict__ points,
                                             const float* __restrict__ queries,
                                             int*   __restrict__ idxbuf,
                                             float* __restrict__ local4,
                                             float* __restrict__ p1)
{
#pragma clang fp contract(off)
    __shared__ float4 pt[N_];                    // x,y,z,pn  (32 KB)
    __shared__ unsigned           bufA[4][64];   // 1 KB
    __shared__ unsigned long long bufB[4][64];   // 2 KB
    __shared__ float  wred[4][8];

    const int t    = threadIdx.x;
    const int lane = t & 63;
    const int wv   = t >> 6;
    const int bl   = blockIdx.x >> 8;            // 256 WGs per bl
    const int m    = ((blockIdx.x & 255) << 2) + wv;

    const float* P = points  + (size_t)bl * (N_*3);
    const float* Q = queries + (size_t)bl * (M_*3);

    for (int n = t; n < N_; n += 256) {
        float x = P[n*3], y = P[n*3+1], z = P[n*3+2];
        float pn = (x*x + y*y) + z*z;            // left-assoc, no FMA
        pt[n] = make_float4(x, y, z, pn);
    }
    __syncthreads();

    const float qx = Q[m*3], qy = Q[m*3+1], qz = Q[m*3+2];
    const float qn = (qx*qx + qy*qy) + qz*qz;
    const double qxd = (double)qx, qyd = (double)qy, qzd = (double)qz;

    // distributed top-32 state: lane i of 0..31 = i-th smallest; 32..63 = +inf
    unsigned           Aa = 0xFFFFFFFFu;
    unsigned long long Ab = ~0ULL;
    unsigned           thrA = 0xFFFFFFFFu;       // running 32nd-smallest
    unsigned long long thrB = ~0ULL;
    int bufcnt = 0;                              // wave-uniform

    auto flushfn = [&]() {
        unsigned sa = 0xFFFFFFFFu; unsigned long long sb = ~0ULL;
        if (lane < bufcnt) { sa = bufA[wv][lane]; sb = bufB[wv][lane]; }
        // 64-lane bitonic sort ascending
        for (int k = 2; k <= 64; k <<= 1) {
            for (int j = k >> 1; j >= 1; j >>= 1) {
                unsigned           pa = __shfl_xor(sa, j);
                unsigned long long pb = shfl_xor_u64(sb, j);
                bool pl = (pa < sa) || (pa == sa && pb < sb);
                bool wantMin = (((lane & k) == 0) == ((lane & j) == 0));
                if (pl == wantMin) { sa = pa; sb = pb; }
            }
        }
        // lower-half merge: M_i = min(A_i, S_{31-i}) on lanes 0..31
        int src = (31 - lane) & 63;
        unsigned           ba  = __shfl(sa, src);
        unsigned long long bb2 = shfl_u64(sb, src);
        if (lane < 32) {
            bool bless = (ba < Aa) || (ba == Aa && bb2 < Ab);
            if (bless) { Aa = ba; Ab = bb2; }
        }
        // resort (bitonic -> ascending) within lanes 0..31
        for (int j = 16; j >= 1; j >>= 1) {
            unsigned           pa = __shfl_xor(Aa, j);
            unsigned long long pb = shfl_xor_u64(Ab, j);
            bool pl = (pa < Aa) || (pa == Aa && pb < Ab);
            bool wantMin = ((lane & j) == 0);
            if (pl == wantMin) { Aa = pa; Ab = pb; }
        }
        bufcnt = 0;
        thrA = __shfl(Aa, 31); thrB = shfl_u64(Ab, 31);
    };

    for (int r = 0; r < 32; ++r) {
        const int n = r*64 + lane;
        const float4 p4 = pt[n];
        float cross = (qx*p4.x + qy*p4.y) + qz*p4.z;   // no FMA
        float d2f = (qn + p4.w) - 2.0f*cross;
        unsigned uA = __float_as_uint(d2f);
        uA = (uA & 0x80000000u) ? ~uA : (uA | 0x80000000u);
        double dx = qxd - (double)p4.x, dy = qyd - (double)p4.y, dz = qzd - (double)p4.z;
        double d2d = dx*dx + dy*dy + dz*dz;
        unsigned long long uB = (unsigned long long)__double_as_longlong(d2d);
        uB = (uB & 0x8000000000000000ULL) ? ~uB : (uB | 0x8000000000000000ULL);
        uB = (uB & ~2047ULL) | (unsigned long long)n;

        bool lt = (uA < thrA) || (uA == thrA && uB < thrB);
        unsigned long long mask = __ballot(lt);
        int cnt = __builtin_popcountll(mask);
        if (cnt == 0) continue;
        if (bufcnt + cnt > 64) {
            flushfn();
            lt = (uA < thrA) || (uA == thrA && uB < thrB);
            mask = __ballot(lt);
            cnt = __builtin_popcountll(mask);
            if (cnt == 0) continue;
        }
        int pos = bufcnt + __builtin_popcountll(mask & ((1ULL << lane) - 1ULL));
        if (lt) { bufA[wv][pos] = uA; bufB[wv][pos] = uB; }
        bufcnt += cnt;
    }
    if (bufcnt > 0) flushfn();

    const long long base = ((long long)bl * M_ + m) * K_;
    float lx = 0.f, ly = 0.f, lz = 0.f;
    if (lane < 32) {
        const int n = (int)(Ab & 2047ULL);
        idxbuf[base + lane] = n;
        const float4 p4 = pt[n];
        lx = qx - p4.x; ly = qy - p4.y; lz = qz - p4.z;
        *(float4*)(local4 + (base + lane)*4) = make_float4(lx, ly, lz, 0.f);
    }
    float s0 = lx, s1 = ly, s2 = lz, s3 = lx*lx, s4 = ly*ly, s5 = lz*lz;
#pragma unroll
    for (int off = 32; off; off >>= 1) {
        s0 += __shfl_xor(s0, off); s1 += __shfl_xor(s1, off); s2 += __shfl_xor(s2, off);
        s3 += __shfl_xor(s3, off); s4 += __shfl_xor(s4, off); s5 += __shfl_xor(s5, off);
    }
    if (lane == 0) {
        wred[wv][0]=s0; wred[wv][1]=s1; wred[wv][2]=s2;
        wred[wv][3]=s3; wred[wv][4]=s4; wred[wv][5]=s5;
    }
    __syncthreads();
    if (t < 6)
        p1[(long long)blockIdx.x*8 + t] = wred[0][t]+wred[1][t]+wred[2][t]+wred[3][t];
}

// =====================================================================
// fold1: reduce 2048 WG partials, fold bn1 into w1/b1
// =====================================================================
__global__ __launch_bounds__(256) void k_fold1(const float* __restrict__ p1,
                        const float* __restrict__ w1, const float* __restrict__ b1,
                        const float* __restrict__ g,  const float* __restrict__ bb,
                        float* __restrict__ w1f, float* __restrict__ b1f)
{
    __shared__ float red[6][33];
    __shared__ float s1[3], t1[3];
    const int t = threadIdx.x;
    const int c = t >> 5, i = t & 31;
    if (c < 6) {
        float s = 0.f;
        for (int w = i; w < 2048; w += 32) s += p1[w*8 + c];
        red[c][i] = s;
    }
    __syncthreads();
    if (t < 3) {
        float S = 0.f, Q = 0.f;
        for (int k = 0; k < 32; ++k) { S += red[t][k]; Q += red[t+3][k]; }
        float mean = S / (float)NPTS_;
        float var  = Q / (float)NPTS_ - mean*mean;
        float r = 1.0f / sqrtf(var + EPS_);
        float sc = r * g[t];
        s1[t] = sc; t1[t] = bb[t] - mean*sc;
    }
    __syncthreads();
    if (t < 32) {
        float acc = b1[t];
        for (int i2 = 0; i2 < 3; ++i2) {
            float w = w1[t*3+i2];
            w1f[t*3+i2] = w * s1[i2];
            acc += w * t1[i2];
        }
        b1f[t] = acc;
    }
}

// =====================================================================
// K2: bn2 stats (recompute h1 = relu(w1f.local + b1f))
// =====================================================================
__global__ __launch_bounds__(256) void k_stats2(const float* __restrict__ local4,
                                                const float* __restrict__ w1f,
                                                const float* __restrict__ b1f,
                                                float* __restrict__ p2)
{
    __shared__ float ws[96], bs[32];
    __shared__ float red[256][33];
    int t = threadIdx.x;
    for (int j = t; j < 96; j += 256) ws[j] = w1f[j];
    if (t < 32) bs[t] = b1f[t];
    __syncthreads();

    float s[32], q[32];
#pragma unroll
    for (int o = 0; o < 32; ++o) { s[o] = 0.f; q[o] = 0.f; }
    const int base = blockIdx.x * 1024;
    for (int i = 0; i < 4; ++i) {
        const float4 v = *(const float4*)(local4 + (size_t)(base + i*256 + t) * 4);
#pragma unroll
        for (int o = 0; o < 32; ++o) {
            float h = fmaxf(bs[o] + ws[o*3]*v.x + ws[o*3+1]*v.y + ws[o*3+2]*v.z, 0.f);
            s[o] += h; q[o] += h*h;
        }
    }
#pragma unroll
    for (int o = 0; o < 32; ++o) red[t][o] = s[o];
    __syncthreads();
    for (int h = 128; h > 0; h >>= 1) {
        if (t < h) { for (int o = 0; o < 32; ++o) red[t][o] += red[t+h][o]; }
        __syncthreads();
    }
    if (t < 32) p2[blockIdx.x*64 + t] = red[0][t];
    __syncthreads();
#pragma unroll
    for (int o = 0; o < 32; ++o) red[t][o] = q[o];
    __syncthreads();
    for (int h = 128; h > 0; h >>= 1) {
        if (t < h) { for (int o = 0; o < 32; ++o) red[t][o] += red[t+h][o]; }
        __syncthreads();
    }
    if (t < 32) p2[blockIdx.x*64 + 32 + t] = red[0][t];
}

// =====================================================================
// fold2: bn2 stats -> fold into w2/b2
// =====================================================================
__global__ void k_fold2(const float* __restrict__ p2,
                        const float* __restrict__ w2, const float* __restrict__ b2,
                        const float* __restrict__ g,  const float* __restrict__ bb,
                        float* __restrict__ w2f, float* __restrict__ b2f)
{
    __shared__ float s2[32], t2[32];
    int t = threadIdx.x;   // 64
    if (t < 32) {
        float S = 0, Q = 0;
        for (int b = 0; b < 256; ++b) { S += p2[b*64+t]; Q += p2[b*64+32+t]; }
        float mean = S / (float)NPTS_;
        float var  = Q / (float)NPTS_ - mean*mean;
        float r = 1.0f / sqrtf(var + EPS_);
        float sc = r * g[t];
        s2[t] = sc; t2[t] = bb[t] - mean*sc;
    }
    __syncthreads();
    float acc = b2[t];
    for (int i = 0; i < 32; ++i) {
        float w = w2[t*32+i];
        w2f[t*32+i] = w * s2[i];
        acc += w * t2[i];
    }
    b2f[t] = acc;
}

// =====================================================================
// K3: per-(b,l,m): h1 -> h2, gather feat_prev, shell maxpool -> fm row
// =====================================================================
__global__ __launch_bounds__(256) void k_shell(const float* __restrict__ feat_prev,
                                               const int*   __restrict__ idxbuf,
                                               const float* __restrict__ local4,
                                               const float* __restrict__ w1f,
                                               const float* __restrict__ b1f,
                                               const float* __restrict__ w2f,
                                               const float* __restrict__ b2f,
                                               float* __restrict__ fm)
{
    __shared__ float w1s[96], b1s[32], w2s[32][64], b2s[64];
    __shared__ int   idxs[K_];
    __shared__ float locs[K_][4];
    __shared__ float h1s[K_][33];
    __shared__ float h2s[K_][65];
    __shared__ float fmrow[DIV_][CIN_];

    const int t = threadIdx.x;
    const int blm = blockIdx.x;
    const long long base = (long long)blm * K_;

    for (int j = t; j < 96; j += 256) w1s[j] = w1f[j];
    if (t < 32) b1s[t] = b1f[t];
    if (t < 64) b2s[t] = b2f[t];
    for (int j = t; j < 2048; j += 256) { int i = j >> 6, o = j & 63; w2s[i][o] = w2f[o*32 + i]; }
    if (t < 32)  idxs[t] = idxbuf[base + t];
    if (t < 128) ((float*)locs)[t] = local4[base*4 + t];
    __syncthreads();

    for (int j = t; j < 1024; j += 256) {
        int k = j >> 5, o = j & 31;
        float v = b1s[o] + w1s[o*3]*locs[k][0] + w1s[o*3+1]*locs[k][1] + w1s[o*3+2]*locs[k][2];
        h1s[k][o] = fmaxf(v, 0.f);
    }
    __syncthreads();
    for (int j = t; j < 2048; j += 256) {
        int k = j >> 6, o = j & 63;
        float acc = b2s[o];
#pragma unroll
        for (int i = 0; i < 32; ++i) acc += h1s[k][i] * w2s[i][o];
        h2s[k][o] = fmaxf(acc, 0.f);
    }
    __syncthreads();
    {
        int d = t >> 6, o = t & 63;
        float mx = h2s[d*8][o];
#pragma unroll
        for (int j = 1; j < 8; ++j) mx = fmaxf(mx, h2s[d*8+j][o]);
        fmrow[d][o] = mx;
    }
    {
        const float* fp0 = feat_prev + (size_t)(blm / M_) * N_ * F1_;
#pragma unroll
        for (int ph = 0; ph < 2; ++ph) {
            int d = ph*2 + (t >> 7), c = t & 127;
            float mx = -3.4e38f;
#pragma unroll
            for (int j = 0; j < 8; ++j) {
                int n = idxs[d*8+j];
                mx = fmaxf(mx, fp0[(size_t)n*F1_ + c]);
            }
            fmrow[d][64 + c] = mx;
        }
    }
    __syncthreads();
    for (int j = t; j < DIV_*CIN_; j += 256)
        fm[(long long)blm * (DIV_*CIN_) + j] = (&fmrow[0][0])[j];
}

// =====================================================================
// K3s: bnc stats over fm (32768 rows x 192 ch)
// =====================================================================
__global__ void k_stats3(const float* __restrict__ fm, float* __restrict__ p3)
{
    const int t = threadIdx.x;     // 192
    const int blk = blockIdx.x;    // 128
    float s = 0.f, q = 0.f;
    const size_t base = (size_t)blk * 256 * CIN_;
    for (int r = 0; r < 256; ++r) {
        float v = fm[base + (size_t)r*CIN_ + t];
        s += v; q += v*v;
    }
    p3[blk*384 + t] = s;
    p3[blk*384 + 192 + t] = q;
}

// =====================================================================
// fold3: bnc stats -> scaled transposed conv weights + effective bias
// =====================================================================
__global__ __launch_bounds__(256) void k_fold3(const float* __restrict__ p3,
                                               const float* __restrict__ conv_w,
                                               const float* __restrict__ conv_b,
                                               const float* __restrict__ g,
                                               const float* __restrict__ bb,
                                               float* __restrict__ wcfT,
                                               float* __restrict__ bcf)
{
    __shared__ float sc[CIN_], tc[CIN_];
    const int t = threadIdx.x;
    if (t < CIN_) {
        float S = 0, Q = 0;
        for (int b = 0; b < 128; ++b) { S += p3[b*384+t]; Q += p3[b*384+192+t]; }
        float mean = S / (float)ROWS_;
        float var  = Q / (float)ROWS_ - mean*mean;
        float r = 1.0f / sqrtf(var + EPS_);
        float s = r * g[t];
        sc[t] = s; tc[t] = bb[t] - mean*s;
    }
    __syncthreads();
    const int lo = blockIdx.x * 3072;
    for (int j = lo + t; j < lo + 3072; j += 256) {
        int o = j & 255, row = j >> 8;
        int c = row % CIN_, d = row / CIN_;
        wcfT[j] = conv_w[o*768 + c*4 + d] * sc[c];
    }
    if (blockIdx.x == 0) {
        float acc = conv_b[t];
        for (int c = 0; c < CIN_; ++c) {
            float tcv = tc[c];
#pragma unroll
            for (int d = 0; d < 4; ++d) acc += tcv * conv_w[t*768 + c*4 + d];
        }
        bcf[t] = acc;
    }
}

// =====================================================================
// K4: GEMM  C(8192x256) = fm(8192x768) * wcfT(768x256) + bcf
// =====================================================================
__global__ __launch_bounds__(256) void k_gemm(const float* __restrict__ A,
                                              const float* __restrict__ W,
                                              const float* __restrict__ bias,
                                              float* __restrict__ C)
{
    __shared__ __align__(16) float At[32][68];
    __shared__ __align__(16) float Wt[32][64];
    const int tx = threadIdx.x, ty = threadIdx.y;
    const int t = ty*16 + tx;
    const int row0 = blockIdx.x * 64, col0 = blockIdx.y * 64;

    float acc[4][4];
#pragma unroll
    for (int i = 0; i < 4; ++i)
#pragma unroll
        for (int j = 0; j < 4; ++j) acc[i][j] = 0.f;

    for (int kt = 0; kt < 24; ++kt) {
#pragma unroll
        for (int i = 0; i < 8; ++i) {
            int j = i*256 + t; int r = j >> 5, k = j & 31;
            At[k][r] = A[(size_t)(row0 + r)*768 + kt*32 + k];
        }
#pragma unroll
        for (int i = 0; i < 8; ++i) {
            int j = i*256 + t; int k = j >> 6, c = j & 63;
            Wt[k][c] = W[(size_t)(kt*32 + k)*256 + col0 + c];
        }
        __syncthreads();
#pragma unroll
        for (int k = 0; k < 32; ++k) {
            float4 a = *(const float4*)&At[k][ty*4];
            float4 w = *(const float4*)&Wt[k][tx*4];
            acc[0][0] += a.x*w.x; acc[0][1] += a.x*w.y; acc[0][2] += a.x*w.z; acc[0][3] += a.x*w.w;
            acc[1][0] += a.y*w.x; acc[1][1] += a.y*w.y; acc[1][2] += a.y*w.z; acc[1][3] += a.y*w.w;
            acc[2][0] += a.z*w.x; acc[2][1] += a.z*w.y; acc[2][2] += a.z*w.z; acc[2][3] += a.z*w.w;
            acc[3][0] += a.w*w.x; acc[3][1] += a.w*w.y; acc[3][2] += a.w*w.z; acc[3][3] += a.w*w.w;
        }
        __syncthreads();
    }

    float b4[4];
#pragma unroll
    for (int j = 0; j < 4; ++j) b4[j] = bias[col0 + tx*4 + j];
#pragma unroll
    for (int i = 0; i < 4; ++i) {
        int r = row0 + ty*4 + i;
        float4 o4;
        o4.x = acc[i][0] + b4[0];
        o4.y = acc[i][1] + b4[1];
        o4.z = acc[i][2] + b4[2];
        o4.w = acc[i][3] + b4[3];
        *(float4*)&C[(size_t)r*256 + col0 + tx*4] = o4;
    }
}

// =====================================================================
extern "C" void kernel_launch(void* const* d_in, const int* in_sizes, int n_in,
                              void* d_out, int out_size, void* d_ws, size_t ws_size,
                              hipStream_t stream)
{
    const float* points    = (const float*)d_in[0];
    const float* queries   = (const float*)d_in[1];
    const float* feat_prev = (const float*)d_in[2];
    const float* bn1g = (const float*)d_in[3];
    const float* bn1b = (const float*)d_in[4];
    const float* w1   = (const float*)d_in[5];
    const float* b1   = (const float*)d_in[6];
    const float* bn2g = (const float*)d_in[7];
    const float* bn2b = (const float*)d_in[8];
    const float* w2   = (const float*)d_in[9];
    const float* b2   = (const float*)d_in[10];
    const float* bncg = (const float*)d_in[11];
    const float* bncb = (const float*)d_in[12];
    const float* convw= (const float*)d_in[13];
    const float* convb= (const float*)d_in[14];

    float* ws   = (float*)d_ws;
    float* fm   = ws + OFF_FM;
    int*   idxb = (int*)(ws + OFF_IDX);
    float* loc4 = ws + OFF_LOC;
    float* w1f  = ws + OFF_W1F;
    float* b1f  = ws + OFF_B1F;
    float* w2f  = ws + OFF_W2F;
    float* b2f  = ws + OFF_B2F;
    float* wct  = ws + OFF_WCT;
    float* bcf  = ws + OFF_BCF;
    float* p1   = ws + OFF_FM;     // aliases fm head; consumed by fold1 before k_shell writes fm
    float* p2   = ws + OFF_P2;
    float* p3   = ws + OFF_P3;

    k_knn   <<<2048, 256, 0, stream>>>(points, queries, idxb, loc4, p1);
    k_fold1 <<<1, 256, 0, stream>>>(p1, w1, b1, bn1g, bn1b, w1f, b1f);
    k_stats2<<<256, 256, 0, stream>>>(loc4, w1f, b1f, p2);
    k_fold2 <<<1, 64, 0, stream>>>(p2, w2, b2, bn2g, bn2b, w2f, b2f);
    k_shell <<<BLM_, 256, 0, stream>>>(feat_prev, idxb, loc4, w1f, b1f, w2f, b2f, fm);
    k_stats3<<<128, 192, 0, stream>>>(fm, p3);
    k_fold3 <<<64, 256, 0, stream>>>(p3, convw, convb, bncg, bncb, wct, bcf);
    k_gemm  <<<dim3(128, 4), dim3(16, 16), 0, stream>>>(fm, wct, bcf, (float*)d_out);
}

// Round 10
// 216.176 us; speedup vs baseline: 31.8116x; 1.1275x over previous
//
#include <hip/hip_runtime.h>
#include <cstdint>

// ---- problem constants ----
#define B_    2
#define L_    4
#define N_    2048
#define M_    1024
#define K_    32
#define DIV_  4
#define S_    8
#define F1_   128
#define PF_   64
#define CIN_  192
#define OUT_  256
#define EPS_  1e-5f

#define BL_   (B_*L_)          // 8
#define BLM_  (BL_*M_)         // 8192
#define NPTS_ (BLM_*K_)        // 262144
#define ROWS_ (BLM_*DIV_)      // 32768

// ---- workspace layout (float offsets) ----
#define OFF_FM   0              // 6291456   fm: [BLM][4][192]  (p1 aliases its head pre-k_shell)
#define OFF_IDX  6291456        // 262144    idx (int)
#define OFF_LOC  6553600        // 1048576   local4: [NPTS][4]
#define OFF_W1F  7602176        // 96
#define OFF_B1F  7602272        // 32
#define OFF_W2F  7602304        // 2048
#define OFF_B2F  7604352        // 64
#define OFF_WCT  7604416        // 196608    wcfT: [768][256]
#define OFF_BCF  7801024        // 256
#define OFF_P2   7801536        // 16384     (256 blocks x 64)
#define OFF_P3   7817920        // 49152     (128 blocks x 384)

__device__ __forceinline__ unsigned long long shfl_xor_u64(unsigned long long v, int m)
{
    unsigned lo = (unsigned)v, hi = (unsigned)(v >> 32);
    lo = __shfl_xor(lo, m); hi = __shfl_xor(hi, m);
    return ((unsigned long long)hi << 32) | lo;
}
__device__ __forceinline__ unsigned long long shfl_u64(unsigned long long v, int src)
{
    unsigned lo = (unsigned)v, hi = (unsigned)(v >> 32);
    lo = __shfl(lo, src); hi = __shfl(hi, src);
    return ((unsigned long long)hi << 32) | lo;
}

// =====================================================================
// K1: wave-per-query KNN, lane-distributed top-32, filter + batched
// bitonic rebuild, LAZY f64 secondary key (computed only at flush).
// Key semantics IDENTICAL to the passing rounds 6/8/9:
//   primary   uA = ordered-bits of expanded-f32 d2 = (qn+pn) - 2*cross
//             (no FMA, left-assoc, contract(off))
//   secondary uB = ordered-bits of f64 direct d2, low 11 bits = index
// Filter admits uA <= thrA (superset of the exact predicate; rejected
// candidates have uA > thrA >= final 32nd primary -> exact). Flush
// recomputes uB for the <=64 buffered survivors only.
// =====================================================================
__global__ __launch_bounds__(256) void k_knn(const float* __restrict__ points,
                                             const float* __restrict__ queries,
                                             int*   __restrict__ idxbuf,
                                             float* __restrict__ local4,
                                             float* __restrict__ p1)
{
#pragma clang fp contract(off)
    __shared__ float4 pt[N_];                    // x,y,z,pn  (32 KB)
    __shared__ unsigned bufA[4][64];             // 1 KB
    __shared__ int      bufN[4][64];             // 1 KB
    __shared__ float  wred[4][8];

    const int t    = threadIdx.x;
    const int lane = t & 63;
    const int wv   = t >> 6;
    const int bl   = blockIdx.x >> 8;            // 256 WGs per bl
    const int m    = ((blockIdx.x & 255) << 2) + wv;

    const float* P = points  + (size_t)bl * (N_*3);
    const float* Q = queries + (size_t)bl * (M_*3);

    for (int n = t; n < N_; n += 256) {
        float x = P[n*3], y = P[n*3+1], z = P[n*3+2];
        float pn = (x*x + y*y) + z*z;            // left-assoc, no FMA
        pt[n] = make_float4(x, y, z, pn);
    }
    __syncthreads();

    const float qx = Q[m*3], qy = Q[m*3+1], qz = Q[m*3+2];
    const float qn = (qx*qx + qy*qy) + qz*qz;
    const double qxd = (double)qx, qyd = (double)qy, qzd = (double)qz;

    // distributed top-32 state: lane i of 0..31 = i-th smallest; 32..63 = +inf
    unsigned           Aa = 0xFFFFFFFFu;
    unsigned long long Ab = ~0ULL;
    unsigned           thrA = 0xFFFFFFFFu;       // running 32nd-smallest primary
    int bufcnt = 0;                              // wave-uniform

    auto flushfn = [&]() {
        unsigned sa = 0xFFFFFFFFu; unsigned long long sb = ~0ULL;
        if (lane < bufcnt) {
            sa = bufA[wv][lane];
            const int n = bufN[wv][lane];
            const float4 p4 = pt[n];
            double dx = qxd - (double)p4.x, dy = qyd - (double)p4.y, dz = qzd - (double)p4.z;
            double d2d = dx*dx + dy*dy + dz*dz;
            unsigned long long uB = (unsigned long long)__double_as_longlong(d2d);
            uB = (uB & 0x8000000000000000ULL) ? ~uB : (uB | 0x8000000000000000ULL);
            sb = (uB & ~2047ULL) | (unsigned long long)n;
        }
        // 64-lane bitonic sort ascending (lexicographic)
        for (int k = 2; k <= 64; k <<= 1) {
            for (int j = k >> 1; j >= 1; j >>= 1) {
                unsigned           pa = __shfl_xor(sa, j);
                unsigned long long pb = shfl_xor_u64(sb, j);
                bool pl = (pa < sa) || (pa == sa && pb < sb);
                bool wantMin = (((lane & k) == 0) == ((lane & j) == 0));
                if (pl == wantMin) { sa = pa; sb = pb; }
            }
        }
        // lower-half merge: M_i = min(A_i, S_{31-i}) on lanes 0..31
        int src = (31 - lane) & 63;
        unsigned           ba  = __shfl(sa, src);
        unsigned long long bb2 = shfl_u64(sb, src);
        if (lane < 32) {
            bool bless = (ba < Aa) || (ba == Aa && bb2 < Ab);
            if (bless) { Aa = ba; Ab = bb2; }
        }
        // resort (bitonic -> ascending) within lanes 0..31
        for (int j = 16; j >= 1; j >>= 1) {
            unsigned           pa = __shfl_xor(Aa, j);
            unsigned long long pb = shfl_xor_u64(Ab, j);
            bool pl = (pa < Aa) || (pa == Aa && pb < Ab);
            bool wantMin = ((lane & j) == 0);
            if (pl == wantMin) { Aa = pa; Ab = pb; }
        }
        bufcnt = 0;
        thrA = __shfl(Aa, 31);
    };

    for (int r = 0; r < 32; ++r) {
        const int n = r*64 + lane;
        const float4 p4 = pt[n];
        float cross = (qx*p4.x + qy*p4.y) + qz*p4.z;   // no FMA
        float d2f = (qn + p4.w) - 2.0f*cross;
        unsigned uA = __float_as_uint(d2f);
        uA = (uA & 0x80000000u) ? ~uA : (uA | 0x80000000u);

        bool lt = (uA <= thrA);
        unsigned long long mask = __ballot(lt);
        int cnt = __builtin_popcountll(mask);
        if (cnt == 0) continue;
        if (bufcnt + cnt > 64) {
            flushfn();
            lt = (uA <= thrA);
            mask = __ballot(lt);
            cnt = __builtin_popcountll(mask);
            if (cnt == 0) continue;
        }
        int pos = bufcnt + __builtin_popcountll(mask & ((1ULL << lane) - 1ULL));
        if (lt) { bufA[wv][pos] = uA; bufN[wv][pos] = n; }
        bufcnt += cnt;
    }
    if (bufcnt > 0) flushfn();

    const long long base = ((long long)bl * M_ + m) * K_;
    float lx = 0.f, ly = 0.f, lz = 0.f;
    if (lane < 32) {
        const int n = (int)(Ab & 2047ULL);
        idxbuf[base + lane] = n;
        const float4 p4 = pt[n];
        lx = qx - p4.x; ly = qy - p4.y; lz = qz - p4.z;
        *(float4*)(local4 + (base + lane)*4) = make_float4(lx, ly, lz, 0.f);
    }
    float s0 = lx, s1 = ly, s2 = lz, s3 = lx*lx, s4 = ly*ly, s5 = lz*lz;
#pragma unroll
    for (int off = 32; off; off >>= 1) {
        s0 += __shfl_xor(s0, off); s1 += __shfl_xor(s1, off); s2 += __shfl_xor(s2, off);
        s3 += __shfl_xor(s3, off); s4 += __shfl_xor(s4, off); s5 += __shfl_xor(s5, off);
    }
    if (lane == 0) {
        wred[wv][0]=s0; wred[wv][1]=s1; wred[wv][2]=s2;
        wred[wv][3]=s3; wred[wv][4]=s4; wred[wv][5]=s5;
    }
    __syncthreads();
    if (t < 6)
        p1[(long long)blockIdx.x*8 + t] = wred[0][t]+wred[1][t]+wred[2][t]+wred[3][t];
}

// =====================================================================
// fold1: reduce 2048 WG partials, fold bn1 into w1/b1
// =====================================================================
__global__ __launch_bounds__(256) void k_fold1(const float* __restrict__ p1,
                        const float* __restrict__ w1, const float* __restrict__ b1,
                        const float* __restrict__ g,  const float* __restrict__ bb,
                        float* __restrict__ w1f, float* __restrict__ b1f)
{
    __shared__ float red[6][33];
    __shared__ float s1[3], t1[3];
    const int t = threadIdx.x;
    const int c = t >> 5, i = t & 31;
    if (c < 6) {
        float s = 0.f;
        for (int w = i; w < 2048; w += 32) s += p1[w*8 + c];
        red[c][i] = s;
    }
    __syncthreads();
    if (t < 3) {
        float S = 0.f, Q = 0.f;
        for (int k = 0; k < 32; ++k) { S += red[t][k]; Q += red[t+3][k]; }
        float mean = S / (float)NPTS_;
        float var  = Q / (float)NPTS_ - mean*mean;
        float r = 1.0f / sqrtf(var + EPS_);
        float sc = r * g[t];
        s1[t] = sc; t1[t] = bb[t] - mean*sc;
    }
    __syncthreads();
    if (t < 32) {
        float acc = b1[t];
        for (int i2 = 0; i2 < 3; ++i2) {
            float w = w1[t*3+i2];
            w1f[t*3+i2] = w * s1[i2];
            acc += w * t1[i2];
        }
        b1f[t] = acc;
    }
}

// =====================================================================
// K2: bn2 stats — lane-per-channel accumulation, shfl reduce.
// Each block: stage 1024 local4 rows to LDS (coalesced), each wave
// processes its 256 rows two-at-a-time (half-wave per row, channel=lane&31),
// then shfl_xor(32) + tiny LDS cross-wave reduce.
// =====================================================================
__global__ __launch_bounds__(256) void k_stats2(const float* __restrict__ local4,
                                                const float* __restrict__ w1f,
                                                const float* __restrict__ b1f,
                                                float* __restrict__ p2)
{
    __shared__ float4 pts[1024];       // 16 KB
    __shared__ float  sred[4][64];
    const int t = threadIdx.x;
    const int lane = t & 63;
    const int wv   = t >> 6;
    const int base = blockIdx.x * 1024;

    for (int j = t; j < 1024; j += 256)
        pts[j] = *(const float4*)(local4 + (size_t)(base + j) * 4);

    const int ch = lane & 31;
    const float w0 = w1f[ch*3], w1v = w1f[ch*3+1], w2v = w1f[ch*3+2];
    const float bv = b1f[ch];
    __syncthreads();

    float s = 0.f, q = 0.f;
    const int pbase = wv*256 + (lane >> 5);      // half-wave -> row parity
    for (int it = 0; it < 128; ++it) {
        float4 v = pts[pbase + it*2];
        float h = fmaxf(bv + w0*v.x + w1v*v.y + w2v*v.z, 0.f);
        s += h; q += h*h;
    }
    s += __shfl_xor(s, 32); q += __shfl_xor(q, 32);
    if (lane < 32) { sred[wv][lane] = s; sred[wv][32+lane] = q; }
    __syncthreads();
    if (t < 64)
        p2[blockIdx.x*64 + t] = sred[0][t]+sred[1][t]+sred[2][t]+sred[3][t];
}

// =====================================================================
// fold2: bn2 stats -> fold into w2/b2
// =====================================================================
__global__ void k_fold2(const float* __restrict__ p2,
                        const float* __restrict__ w2, const float* __restrict__ b2,
                        const float* __restrict__ g,  const float* __restrict__ bb,
                        float* __restrict__ w2f, float* __restrict__ b2f)
{
    __shared__ float s2[32], t2[32];
    int t = threadIdx.x;   // 64
    if (t < 32) {
        float S = 0, Q = 0;
        for (int b = 0; b < 256; ++b) { S += p2[b*64+t]; Q += p2[b*64+32+t]; }
        float mean = S / (float)NPTS_;
        float var  = Q / (float)NPTS_ - mean*mean;
        float r = 1.0f / sqrtf(var + EPS_);
        float sc = r * g[t];
        s2[t] = sc; t2[t] = bb[t] - mean*sc;
    }
    __syncthreads();
    float acc = b2[t];
    for (int i = 0; i < 32; ++i) {
        float w = w2[t*32+i];
        w2f[t*32+i] = w * s2[i];
        acc += w * t2[i];
    }
    b2f[t] = acc;
}

// =====================================================================
// K3: per-(b,l,m): h1 -> h2 + shell maxpool in registers.
// Wave w owns shell w (k = 8w..8w+7); w2 column in 32 regs/lane
// (channel o = lane); h1 rows via uniform-address b128 broadcasts.
// =====================================================================
__global__ __launch_bounds__(256) void k_shell(const float* __restrict__ feat_prev,
                                               const int*   __restrict__ idxbuf,
                                               const float* __restrict__ local4,
                                               const float* __restrict__ w1f,
                                               const float* __restrict__ b1f,
                                               const float* __restrict__ w2f,
                                               const float* __restrict__ b2f,
                                               float* __restrict__ fm)
{
    __shared__ float w1s[96], b1s[32];
    __shared__ float w2s[64][33];      // w2s[o][i] = w2f[o*32+i], padded
    __shared__ int   idxs[K_];
    __shared__ float locs[K_][4];
    __shared__ __align__(16) float h1s[K_][36];   // rows 16B-aligned (36*4=144)
    __shared__ float fmrow[DIV_][CIN_];

    const int t = threadIdx.x;
    const int lane = t & 63;
    const int wv   = t >> 6;
    const int blm = blockIdx.x;
    const long long base = (long long)blm * K_;

    for (int j = t; j < 96; j += 256) w1s[j] = w1f[j];
    if (t < 32) b1s[t] = b1f[t];
    for (int j = t; j < 2048; j += 256) { int o = j >> 5, i = j & 31; w2s[o][i] = w2f[j]; }
    if (t < 32)  idxs[t] = idxbuf[base + t];
    if (t < 128) ((float*)locs)[t] = local4[base*4 + t];
    __syncthreads();

    for (int j = t; j < 1024; j += 256) {
        int k = j >> 5, o = j & 31;
        float v = b1s[o] + w1s[o*3]*locs[k][0] + w1s[o*3+1]*locs[k][1] + w1s[o*3+2]*locs[k][2];
        h1s[k][o] = fmaxf(v, 0.f);
    }
    __syncthreads();

    // --- h2 + maxpool in registers: wave wv handles shell wv ---
    {
        float w2c[32];
#pragma unroll
        for (int i = 0; i < 32; ++i) w2c[i] = w2s[lane][i];   // (lane+i)%32 banks, 2-way free
        const float b2v = b2f[lane];
        float mx = 0.0f;                                      // relu outputs are >= 0
#pragma unroll
        for (int kk = 0; kk < 8; ++kk) {
            const int k = wv*8 + kk;
            const float4* hp = (const float4*)&h1s[k][0];     // uniform addr -> broadcast
            float acc = b2v;
#pragma unroll
            for (int c = 0; c < 8; ++c) {
                float4 h4 = hp[c];
                acc += h4.x*w2c[c*4+0];
                acc += h4.y*w2c[c*4+1];
                acc += h4.z*w2c[c*4+2];
                acc += h4.w*w2c[c*4+3];
            }
            mx = fmaxf(mx, fmaxf(acc, 0.f));
        }
        fmrow[wv][lane] = mx;
    }
    // --- feat_prev gather + shell maxpool (unchanged) ---
    {
        const float* fp0 = feat_prev + (size_t)(blm / M_) * N_ * F1_;
#pragma unroll
        for (int ph = 0; ph < 2; ++ph) {
            int d = ph*2 + (t >> 7), c = t & 127;
            float mx = -3.4e38f;
#pragma unroll
            for (int j = 0; j < 8; ++j) {
                int n = idxs[d*8+j];
                mx = fmaxf(mx, fp0[(size_t)n*F1_ + c]);
            }
            fmrow[d][64 + c] = mx;
        }
    }
    __syncthreads();
    for (int j = t; j < DIV_*CIN_; j += 256)
        fm[(long long)blm * (DIV_*CIN_) + j] = (&fmrow[0][0])[j];
}

// =====================================================================
// K3s: bnc stats over fm (32768 rows x 192 ch)
// =====================================================================
__global__ void k_stats3(const float* __restrict__ fm, float* __restrict__ p3)
{
    const int t = threadIdx.x;     // 192
    const int blk = blockIdx.x;    // 128
    float s = 0.f, q = 0.f;
    const size_t base = (size_t)blk * 256 * CIN_;
    for (int r = 0; r < 256; ++r) {
        float v = fm[base + (size_t)r*CIN_ + t];
        s += v; q += v*v;
    }
    p3[blk*384 + t] = s;
    p3[blk*384 + 192 + t] = q;
}

// =====================================================================
// fold3: bnc stats -> scaled transposed conv weights + effective bias
// =====================================================================
__global__ __launch_bounds__(256) void k_fold3(const float* __restrict__ p3,
                                               const float* __restrict__ conv_w,
                                               const float* __restrict__ conv_b,
                                               const float* __restrict__ g,
                                               const float* __restrict__ bb,
                                               float* __restrict__ wcfT,
                                               float* __restrict__ bcf)
{
    __shared__ float sc[CIN_], tc[CIN_];
    const int t = threadIdx.x;
    if (t < CIN_) {
        float S = 0, Q = 0;
        for (int b = 0; b < 128; ++b) { S += p3[b*384+t]; Q += p3[b*384+192+t]; }
        float mean = S / (float)ROWS_;
        float var  = Q / (float)ROWS_ - mean*mean;
        float r = 1.0f / sqrtf(var + EPS_);
        float s = r * g[t];
        sc[t] = s; tc[t] = bb[t] - mean*s;
    }
    __syncthreads();
    const int lo = blockIdx.x * 3072;
    for (int j = lo + t; j < lo + 3072; j += 256) {
        int o = j & 255, row = j >> 8;
        int c = row % CIN_, d = row / CIN_;
        wcfT[j] = conv_w[o*768 + c*4 + d] * sc[c];
    }
    if (blockIdx.x == 0) {
        float acc = conv_b[t];
        for (int c = 0; c < CIN_; ++c) {
            float tcv = tc[c];
#pragma unroll
            for (int d = 0; d < 4; ++d) acc += tcv * conv_w[t*768 + c*4 + d];
        }
        bcf[t] = acc;
    }
}

// =====================================================================
// K4: GEMM  C(8192x256) = fm(8192x768) * wcfT(768x256) + bcf
// =====================================================================
__global__ __launch_bounds__(256) void k_gemm(const float* __restrict__ A,
                                              const float* __restrict__ W,
                                              const float* __restrict__ bias,
                                              float* __restrict__ C)
{
    __shared__ __align__(16) float At[32][68];
    __shared__ __align__(16) float Wt[32][64];
    const int tx = threadIdx.x, ty = threadIdx.y;
    const int t = ty*16 + tx;
    const int row0 = blockIdx.x * 64, col0 = blockIdx.y * 64;

    float acc[4][4];
#pragma unroll
    for (int i = 0; i < 4; ++i)
#pragma unroll
        for (int j = 0; j < 4; ++j) acc[i][j] = 0.f;

    for (int kt = 0; kt < 24; ++kt) {
#pragma unroll
        for (int i = 0; i < 8; ++i) {
            int j = i*256 + t; int r = j >> 5, k = j & 31;
            At[k][r] = A[(size_t)(row0 + r)*768 + kt*32 + k];
        }
#pragma unroll
        for (int i = 0; i < 8; ++i) {
            int j = i*256 + t; int k = j >> 6, c = j & 63;
            Wt[k][c] = W[(size_t)(kt*32 + k)*256 + col0 + c];
        }
        __syncthreads();
#pragma unroll
        for (int k = 0; k < 32; ++k) {
            float4 a = *(const float4*)&At[k][ty*4];
            float4 w = *(const float4*)&Wt[k][tx*4];
            acc[0][0] += a.x*w.x; acc[0][1] += a.x*w.y; acc[0][2] += a.x*w.z; acc[0][3] += a.x*w.w;
            acc[1][0] += a.y*w.x; acc[1][1] += a.y*w.y; acc[1][2] += a.y*w.z; acc[1][3] += a.y*w.w;
            acc[2][0] += a.z*w.x; acc[2][1] += a.z*w.y; acc[2][2] += a.z*w.z; acc[2][3] += a.z*w.w;
            acc[3][0] += a.w*w.x; acc[3][1] += a.w*w.y; acc[3][2] += a.w*w.z; acc[3][3] += a.w*w.w;
        }
        __syncthreads();
    }

    float b4[4];
#pragma unroll
    for (int j = 0; j < 4; ++j) b4[j] = bias[col0 + tx*4 + j];
#pragma unroll
    for (int i = 0; i < 4; ++i) {
        int r = row0 + ty*4 + i;
        float4 o4;
        o4.x = acc[i][0] + b4[0];
        o4.y = acc[i][1] + b4[1];
        o4.z = acc[i][2] + b4[2];
        o4.w = acc[i][3] + b4[3];
        *(float4*)&C[(size_t)r*256 + col0 + tx*4] = o4;
    }
}

// =====================================================================
extern "C" void kernel_launch(void* const* d_in, const int* in_sizes, int n_in,
                              void* d_out, int out_size, void* d_ws, size_t ws_size,
                              hipStream_t stream)
{
    const float* points    = (const float*)d_in[0];
    const float* queries   = (const float*)d_in[1];
    const float* feat_prev = (const float*)d_in[2];
    const float* bn1g = (const float*)d_in[3];
    const float* bn1b = (const float*)d_in[4];
    const float* w1   = (const float*)d_in[5];
    const float* b1   = (const float*)d_in[6];
    const float* bn2g = (const float*)d_in[7];
    const float* bn2b = (const float*)d_in[8];
    const float* w2   = (const float*)d_in[9];
    const float* b2   = (const float*)d_in[10];
    const float* bncg = (const float*)d_in[11];
    const float* bncb = (const float*)d_in[12];
    const float* convw= (const float*)d_in[13];
    const float* convb= (const float*)d_in[14];

    float* ws   = (float*)d_ws;
    float* fm   = ws + OFF_FM;
    int*   idxb = (int*)(ws + OFF_IDX);
    float* loc4 = ws + OFF_LOC;
    float* w1f  = ws + OFF_W1F;
    float* b1f  = ws + OFF_B1F;
    float* w2f  = ws + OFF_W2F;
    float* b2f  = ws + OFF_B2F;
    float* wct  = ws + OFF_WCT;
    float* bcf  = ws + OFF_BCF;
    float* p1   = ws + OFF_FM;     // aliases fm head; consumed by fold1 before k_shell writes fm
    float* p2   = ws + OFF_P2;
    float* p3   = ws + OFF_P3;

    k_knn   <<<2048, 256, 0, stream>>>(points, queries, idxb, loc4, p1);
    k_fold1 <<<1, 256, 0, stream>>>(p1, w1, b1, bn1g, bn1b, w1f, b1f);
    k_stats2<<<256, 256, 0, stream>>>(loc4, w1f, b1f, p2);
    k_fold2 <<<1, 64, 0, stream>>>(p2, w2, b2, bn2g, bn2b, w2f, b2f);
    k_shell <<<BLM_, 256, 0, stream>>>(feat_prev, idxb, loc4, w1f, b1f, w2f, b2f, fm);
    k_stats3<<<128, 192, 0, stream>>>(fm, p3);
    k_fold3 <<<64, 256, 0, stream>>>(p3, convw, convb, bncg, bncb, wct, bcf);
    k_gemm  <<<dim3(128, 4), dim3(16, 16), 0, stream>>>(fm, wct, bcf, (float*)d_out);
}